// Round 7
// baseline (183.407 us; speedup 1.0000x reference)
//
#include <hip/hip_runtime.h>
#include <math.h>

#define NN 512   // set size / rows of feat_x
#define IN 512   // INPUT_DIM
#define HD 256   // HIDDEN_DIM
#define RD 256   // REP_DIM
#define SH 128   // SCORE_HIDDEN

// Branchless erf-GELU, Abramowitz-Stegun 7.1.26 (|erf err| <= 1.5e-7).
__device__ __forceinline__ float gelu_fast(float x){
    const float z  = x * 0.70710678118654752f;
    const float az = fabsf(z);
    const float t  = __builtin_amdgcn_rcpf(fmaf(0.3275911f, az, 1.0f));
    float p = fmaf(1.061405429f, t, -1.453152027f);
    p = fmaf(p, t, 1.421413741f);
    p = fmaf(p, t, -0.284496736f);
    p = fmaf(p, t, 0.254829592f);
    p = p * t;
    const float e = __builtin_amdgcn_exp2f(z * z * -1.4426950408889634f);
    const float E = p * e;                        // erfc(|z|)
    const float one_plus_erf = (x >= 0.0f) ? (2.0f - E) : E;
    return 0.5f * x * one_plus_erf;
}

// u*(1+erf(u/sqrt2)) -- the 0.5 is folded into the caller's weight.
// sqrt2 folded into the A&S constants: 0.3275911/sqrt2, ln2-scale/2.
__device__ __forceinline__ float gelu2(float u){
    const float az = fabsf(u);
    const float tt = __builtin_amdgcn_rcpf(fmaf(0.23166045f, az, 1.0f));
    float p = fmaf(1.061405429f, tt, -1.453152027f);
    p = fmaf(p, tt, 1.421413741f);
    p = fmaf(p, tt, -0.284496736f);
    p = fmaf(p, tt, 0.254829592f);
    p = p * tt;
    const float e2 = __builtin_amdgcn_exp2f(u * u * -0.72134752044448170f);
    const float Eq = p * e2;                      // erfc(|u|/sqrt2)
    const float ope = (u >= 0.0f) ? (2.0f - Eq) : Eq;
    return u * ope;
}

// K_REP: fused g-MLP + score-net projections. 768 blocks (3 mats x 256
// 2-row groups) x 256 thr = exactly 3 blocks/CU (balanced). Outputs all
// row-major: r[n][c], A_x[n][k], B_y[m][k]. No transposes anywhere.
__global__ __launch_bounds__(256) void k_rep(
    const float* __restrict__ fx, const float* __restrict__ fp, const float* __restrict__ fn,
    const float* __restrict__ w1, const float* __restrict__ b1,
    const float* __restrict__ w2, const float* __restrict__ b2,
    const float* __restrict__ s_w1,
    float* __restrict__ r_x, float* __restrict__ r_p, float* __restrict__ r_n,
    float* __restrict__ A_x, float* __restrict__ B_p, float* __restrict__ B_n)
{
    __shared__ float xs[2][IN];        // 4 KB
    __shared__ float ps[4][2][HD];     // 8 KB
    __shared__ float hs[2][HD];        // 2 KB
    __shared__ float rloc[2][RD];      // 2 KB
    __shared__ float psf[8][2][SH];    // 8 KB
    const int t = threadIdx.x;
    const int mat = blockIdx.x >> 8;
    const int row0 = (blockIdx.x & 255) << 1;
    const float* src = (mat==0) ? fx : (mat==1) ? fp : fn;

    {   // stage 2 feat rows: 256 float4s
        const int j = t >> 7, q = (t & 127) << 2;
        *(float4*)&xs[j][q] = *(const float4*)&src[(row0+j)*IN + q];
    }
    __syncthreads();

    const int cg = t & 63, s = t >> 6;     // 64 colgroups x 4 K-slices
    const int c0 = cg << 2;

    {   // GEMM1: K=512 in 4 slices of 128
        float4 a0 = make_float4(0.f,0.f,0.f,0.f), a1 = a0;
        const float* wp = w1 + (s*128)*HD + c0;
        #pragma unroll 8
        for (int ii=0; ii<128; ii++){
            float4 w = *(const float4*)wp; wp += HD;
            const int i = s*128 + ii;
            const float x0 = xs[0][i], x1 = xs[1][i];
            a0.x = fmaf(x0, w.x, a0.x); a0.y = fmaf(x0, w.y, a0.y);
            a0.z = fmaf(x0, w.z, a0.z); a0.w = fmaf(x0, w.w, a0.w);
            a1.x = fmaf(x1, w.x, a1.x); a1.y = fmaf(x1, w.y, a1.y);
            a1.z = fmaf(x1, w.z, a1.z); a1.w = fmaf(x1, w.w, a1.w);
        }
        *(float4*)&ps[s][0][c0] = a0;
        *(float4*)&ps[s][1][c0] = a1;
    }
    __syncthreads();

    #pragma unroll
    for (int rep=0; rep<2; rep++){   // reduce + bias + GELU -> hs
        const int idx = rep*256 + t;
        const int j = idx >> 8, c = idx & 255;
        const float v = b1[c] + ps[0][j][c] + ps[1][j][c] + ps[2][j][c] + ps[3][j][c];
        hs[j][c] = gelu_fast(v);
    }
    __syncthreads();

    {   // GEMM2: K=256 in 4 slices of 64
        float4 a0 = make_float4(0.f,0.f,0.f,0.f), a1 = a0;
        const float* wp = w2 + (s*64)*RD + c0;
        #pragma unroll 8
        for (int ii=0; ii<64; ii++){
            float4 w = *(const float4*)wp; wp += RD;
            const int i = s*64 + ii;
            const float x0 = hs[0][i], x1 = hs[1][i];
            a0.x = fmaf(x0, w.x, a0.x); a0.y = fmaf(x0, w.y, a0.y);
            a0.z = fmaf(x0, w.z, a0.z); a0.w = fmaf(x0, w.w, a0.w);
            a1.x = fmaf(x1, w.x, a1.x); a1.y = fmaf(x1, w.y, a1.y);
            a1.z = fmaf(x1, w.z, a1.z); a1.w = fmaf(x1, w.w, a1.w);
        }
        *(float4*)&ps[s][0][c0] = a0;
        *(float4*)&ps[s][1][c0] = a1;
    }
    __syncthreads();

    float* rout = (mat==0) ? r_x : (mat==1) ? r_p : r_n;
    #pragma unroll
    for (int rep=0; rep<2; rep++){   // reduce + bias -> rloc + global r
        const int idx = rep*256 + t;
        const int j = idx >> 8, c = idx & 255;
        const float v = b2[c] + ps[0][j][c] + ps[1][j][c] + ps[2][j][c] + ps[3][j][c];
        rloc[j][c] = v;
        rout[(row0+j)*RD + c] = v;
    }
    __syncthreads();

    {   // score-net projection: 128 cols, K=256 in 8 slices of 32
        const int cg2 = t & 31, s2 = t >> 5;
        const int cc0 = cg2 << 2;
        const float sgn = (mat==0) ? -1.0f : 1.0f;
        const int base1 = (mat==0) ? 0 : 256;
        const float* p1 = s_w1 + (base1 + s2*32)*SH + cc0;
        const float* p3 = s_w1 + (512   + s2*32)*SH + cc0;
        float4 a0 = make_float4(0.f,0.f,0.f,0.f), a1 = a0;
        #pragma unroll 8
        for (int ii=0; ii<32; ii++){
            float4 wa = *(const float4*)p1; p1 += SH;
            float4 wd = *(const float4*)p3; p3 += SH;
            float4 w;
            w.x = fmaf(sgn, wd.x, wa.x);
            w.y = fmaf(sgn, wd.y, wa.y);
            w.z = fmaf(sgn, wd.z, wa.z);
            w.w = fmaf(sgn, wd.w, wa.w);
            const int i = s2*32 + ii;
            const float x0 = rloc[0][i], x1 = rloc[1][i];
            a0.x = fmaf(x0, w.x, a0.x); a0.y = fmaf(x0, w.y, a0.y);
            a0.z = fmaf(x0, w.z, a0.z); a0.w = fmaf(x0, w.w, a0.w);
            a1.x = fmaf(x1, w.x, a1.x); a1.y = fmaf(x1, w.y, a1.y);
            a1.z = fmaf(x1, w.z, a1.z); a1.w = fmaf(x1, w.w, a1.w);
        }
        *(float4*)&psf[s2][0][cc0] = a0;
        *(float4*)&psf[s2][1][cc0] = a1;
    }
    __syncthreads();

    {   // reduce 8 slices: 2 rows x 128 cols = 256 outputs, 1 per thread
        const int j = t >> 7, c = t & 127;
        float v = 0.f;
        #pragma unroll
        for (int ss=0; ss<8; ss++) v += psf[ss][j][c];
        float* dst = (mat==0) ? A_x : (mat==1) ? B_p : B_n;
        dst[(row0+j)*SH + c] = v;       // row-major [n or m][k], coalesced
    }
}

// K_SD: unnormalized softmax numerators. 2048 blocks (set x 256 2-row ntiles
// x 4 128-m mtiles) x 256 thr (= 128 m x 2 k-halves) = 8 blocks/CU, 32 waves.
// Thread = (1 m, 2 rows, half the r/k range); halves combine through LDS.
// All inner-loop global reads are b128 with immediate offsets.
__global__ __launch_bounds__(256) void k_sd(
    const float* __restrict__ r_x, const float* __restrict__ r_p, const float* __restrict__ r_n,
    const float* __restrict__ A_x, const float* __restrict__ B_p, const float* __restrict__ B_n,
    const float* __restrict__ s_w1, const float* __restrict__ s_b1,
    const float* __restrict__ s_w2,
    float* __restrict__ E_p, float* __restrict__ E_n, float* __restrict__ Spart)
{
    __shared__ float4 xs4[2][64];     // 2 KB: x rows as quads
    __shared__ float4 cmb[SH];        // 2 KB: {A0+b1, A1+b1, w_norm, 0.5*w2}
    __shared__ float4 pd[128][2];     // 4 KB: per-(m,half) partials
    __shared__ float nx[2];
    __shared__ float ssum[4];
    const int t = threadIdx.x;
    const int set = blockIdx.x >> 10;
    const int rem = blockIdx.x & 1023;
    const int n0 = (rem >> 2) << 1;
    const int mt = rem & 3;
    const int mbase = mt << 7;
    const int tm = t & 127, kh = t >> 7;
    const int m = mbase + tm;
    const float* ry = set ? r_n : r_p;
    const float* B  = set ? B_n : B_p;
    float* E = set ? E_n : E_p;

    if (t < 128){
        const int j = t >> 6, q = t & 63;
        xs4[j][q] = *(const float4*)&r_x[(n0+j)*RD + (q << 2)];
    } else {
        const int k = t - 128;
        cmb[k] = make_float4(A_x[n0*SH + k] + s_b1[k],
                             A_x[(n0+1)*SH + k] + s_b1[k],
                             s_w1[768*SH + k],
                             0.5f * s_w2[k]);
    }
    __syncthreads();

    // x-row norms (waves 0,1 -> rows 0,1), overlapped with others starting dots
    if (t < 128){
        const int row = t >> 6, lane = t & 63;
        const float4 q = xs4[row][lane];
        float v = q.x*q.x + q.y*q.y + q.z*q.z + q.w*q.w;
        #pragma unroll
        for (int off=32; off>=1; off>>=1) v += __shfl_xor(v, off);
        if (lane==0) nx[row] = v;
    }

    // phase 1: dot(x0,y), dot(x1,y), ||y||^2 over this thread's r-half
    float d0=0.f, d1=0.f, ny=0.f;
    {
        const float* yp = ry + m*RD + (kh << 7);
        #pragma unroll
        for (int q=0; q<32; q++){
            const float4 y = *(const float4*)(yp + (q << 2));   // imm offsets 0..508
            const float4 x0 = xs4[0][(kh << 5) + q];
            const float4 x1 = xs4[1][(kh << 5) + q];
            d0 = fmaf(x0.x,y.x,d0); d0 = fmaf(x0.y,y.y,d0);
            d0 = fmaf(x0.z,y.z,d0); d0 = fmaf(x0.w,y.w,d0);
            d1 = fmaf(x1.x,y.x,d1); d1 = fmaf(x1.y,y.y,d1);
            d1 = fmaf(x1.z,y.z,d1); d1 = fmaf(x1.w,y.w,d1);
            ny = fmaf(y.x,y.x,ny); ny = fmaf(y.y,y.y,ny);
            ny = fmaf(y.z,y.z,ny); ny = fmaf(y.w,y.w,ny);
        }
    }
    pd[tm][kh] = make_float4(d0, d1, ny, 0.f);
    __syncthreads();
    {
        const float4 o = pd[tm][1-kh];
        d0 += o.x; d1 += o.y; ny += o.z;
    }
    const float dn0 = sqrtf(fmaxf(fmaf(-2.f, d0, nx[0] + ny), 0.f));
    const float dn1 = sqrtf(fmaxf(fmaf(-2.f, d1, nx[1] + ny), 0.f));

    // phase 2: logits over this thread's k-half (64 k's, b128 B loads)
    float acc0 = 0.f, acc1 = 0.f;
    {
        const float* bp = B + m*SH + (kh << 6);
        #pragma unroll 4
        for (int q=0; q<16; q++){
            const float4 b4 = *(const float4*)(bp + (q << 2));  // imm offsets 0..252
            const float bb[4] = {b4.x, b4.y, b4.z, b4.w};
            #pragma unroll
            for (int kk=0; kk<4; kk++){
                const float4 c = cmb[(kh << 6) + (q << 2) + kk];
                const float u0 = fmaf(dn0, c.z, c.x + bb[kk]);
                const float u1 = fmaf(dn1, c.z, c.y + bb[kk]);
                acc0 = fmaf(c.w, gelu2(u0), acc0);
                acc1 = fmaf(c.w, gelu2(u1), acc1);
            }
        }
    }
    __syncthreads();                      // protect pd before reuse
    pd[tm][kh] = make_float4(acc0, acc1, 0.f, 0.f);
    __syncthreads();
    {
        const float4 o = pd[tm][1-kh];
        // s_b2 omitted (softmax shift-invariant); no max pass (logits O(1))
        const float tot = (kh==0) ? (acc0 + o.x) : (acc1 + o.y);
        const float ev = __builtin_amdgcn_exp2f(tot * 1.4426950408889634f);
        E[(n0+kh)*NN + m] = ev;
        float v = ev;
        #pragma unroll
        for (int off=32; off>=1; off>>=1) v += __shfl_xor(v, off);
        if ((t & 63) == 0) ssum[t >> 6] = v;
    }
    __syncthreads();
    if (t == 0){
        Spart[(set*4 + mt)*NN + n0]     = ssum[0] + ssum[1];   // row 0 = waves 0,1
        Spart[(set*4 + mt)*NN + n0 + 1] = ssum[2] + ssum[3];   // row 1 = waves 2,3
    }
}

// K_DV: partial einsum over a 64-m slice, both sets combined (pos - neg).
// 1024 blocks (128 4-row ntiles x 8 m-slices). psum[ms][n][c].
__global__ __launch_bounds__(256) void k_dv(
    const float* __restrict__ E_p, const float* __restrict__ E_n,
    const float* __restrict__ Spart,
    const float* __restrict__ r_p, const float* __restrict__ r_n,
    float* __restrict__ psum)
{
    __shared__ float rinv[8];
    __shared__ float wbuf[2][64][4];
    const int t = threadIdx.x;
    const int nt = blockIdx.x >> 3;
    const int ms = blockIdx.x & 7;
    const int n0 = nt << 2, mbase = ms << 6;

    if (t < 8){
        const int se = t >> 2, n = n0 + (t & 3);
        float S = 0.f;
        #pragma unroll
        for (int q=0;q<4;q++) S += Spart[(se*4+q)*NN + n];
        rinv[t] = 1.0f / S;
    }
    __syncthreads();
    #pragma unroll
    for (int rep=0; rep<2; rep++){
        const int idx = rep*256 + t;
        const int se = idx >> 8, j = (idx >> 6) & 3, mm = idx & 63;
        const float* E = se ? E_n : E_p;
        wbuf[se][mm][j] = E[(n0+j)*NN + mbase + mm] * rinv[se*4 + j];
    }
    __syncthreads();

    float acc[4] = {0.f,0.f,0.f,0.f};
    {
        const float* rp = r_p + mbase*RD + t;
        #pragma unroll 4
        for (int mm=0; mm<64; mm++){
            const float rv = *rp; rp += RD;
            const float4 wa = *(const float4*)&wbuf[0][mm][0];
            acc[0]=fmaf(wa.x,rv,acc[0]); acc[1]=fmaf(wa.y,rv,acc[1]);
            acc[2]=fmaf(wa.z,rv,acc[2]); acc[3]=fmaf(wa.w,rv,acc[3]);
        }
    }
    {
        const float* rn = r_n + mbase*RD + t;
        #pragma unroll 4
        for (int mm=0; mm<64; mm++){
            const float rv = -(*rn); rn += RD;
            const float4 wa = *(const float4*)&wbuf[1][mm][0];
            acc[0]=fmaf(wa.x,rv,acc[0]); acc[1]=fmaf(wa.y,rv,acc[1]);
            acc[2]=fmaf(wa.z,rv,acc[2]); acc[3]=fmaf(wa.w,rv,acc[3]);
        }
    }
    float* P = psum + ms*(NN*RD);
    #pragma unroll
    for (int j=0;j<4;j++) P[(n0+j)*RD + t] = acc[j];
}

// K_OUT: dv = sum_ms psum; out = dv @ out_w. 1024 blocks (256 2-row ntiles x
// 4 128-col tiles).
__global__ __launch_bounds__(256) void k_out(
    const float* __restrict__ psum, const float* __restrict__ out_w,
    float* __restrict__ out)
{
    __shared__ float dv2[2][RD];      // 2 KB
    __shared__ float ps[2][2][128];   // 2 KB
    const int t = threadIdx.x;
    const int nt = blockIdx.x >> 2;
    const int cb = (blockIdx.x & 3) << 7;
    const int n0 = nt << 1;

    #pragma unroll
    for (int j=0;j<2;j++){
        float v = 0.f;
        #pragma unroll
        for (int ms=0; ms<8; ms++) v += psum[ms*(NN*RD) + (n0+j)*RD + t];
        dv2[j][t] = v;
    }
    __syncthreads();

    const int cc = t & 127, s = t >> 7;
    float a0 = 0.f, a1 = 0.f;
    const float* wo = out_w + (s*128)*IN + cb + cc;
    #pragma unroll 4
    for (int rr=0; rr<128; rr++){
        const float w = *wo; wo += IN;
        a0 = fmaf(dv2[0][s*128 + rr], w, a0);
        a1 = fmaf(dv2[1][s*128 + rr], w, a1);
    }
    ps[s][0][cc] = a0;
    ps[s][1][cc] = a1;
    __syncthreads();
    {
        const int j = t >> 7, c = t & 127;
        out[(n0+j)*IN + cb + c] = ps[0][j][c] + ps[1][j][c];
    }
}

extern "C" void kernel_launch(void* const* d_in, const int* in_sizes, int n_in,
                              void* d_out, int out_size, void* d_ws, size_t ws_size,
                              hipStream_t stream)
{
    const float* fx  = (const float*)d_in[0];
    const float* fp  = (const float*)d_in[1];
    const float* fn  = (const float*)d_in[2];
    const float* gw1 = (const float*)d_in[3];
    const float* gb1 = (const float*)d_in[4];
    const float* gw2 = (const float*)d_in[5];
    const float* gb2 = (const float*)d_in[6];
    const float* ow  = (const float*)d_in[7];
    const float* sw1 = (const float*)d_in[8];
    const float* sb1 = (const float*)d_in[9];
    const float* sw2 = (const float*)d_in[10];
    float* out = (float*)d_out;

    float* ws   = (float*)d_ws;
    float* r_x  = ws;               // 512*256
    float* r_p  = r_x  + 131072;
    float* r_n  = r_p  + 131072;
    float* A_x  = r_n  + 131072;    // 512*128 row-major [n][k]
    float* B_p  = A_x  + 65536;     // 512*128 row-major [m][k]
    float* B_n  = B_p  + 65536;
    float* E_p  = B_n  + 65536;     // 512*512
    float* E_n  = E_p  + 262144;
    float* Spar = E_n  + 262144;    // 2*4*512
    float* psum = Spar + 4096;      // 8*512*256 (4 MB)

    hipLaunchKernelGGL(k_rep, dim3(768), dim3(256), 0, stream,
                       fx, fp, fn, gw1, gb1, gw2, gb2, sw1,
                       r_x, r_p, r_n, A_x, B_p, B_n);
    hipLaunchKernelGGL(k_sd, dim3(2048), dim3(256), 0, stream,
                       r_x, r_p, r_n, A_x, B_p, B_n,
                       sw1, sb1, sw2, E_p, E_n, Spar);
    hipLaunchKernelGGL(k_dv, dim3(1024), dim3(256), 0, stream,
                       E_p, E_n, Spar, r_p, r_n, psum);
    hipLaunchKernelGGL(k_out, dim3(1024), dim3(256), 0, stream,
                       psum, ow, out);
}